// Round 5
// baseline (85.215 us; speedup 1.0000x reference)
//
#include <hip/hip_runtime.h>

// Problem constants (N=1, D=64, NCLS=21, R=C=512, R_IN=C_IN=256)
#define M_TOT 65536   // R_IN*C_IN
#define LBS_S 262144  // R*C
#define NBINS 1024    // 32x32 bins of 16x16 rp-sites

typedef _Float16 h2 __attribute__((ext_vector_type(2)));
typedef _Float16 h8 __attribute__((ext_vector_type(8)));
union H8 { h8 v; h2 h[4]; };

__device__ __forceinline__ int rfl(int v) { return __builtin_amdgcn_readfirstlane(v); }
__device__ __forceinline__ float bperm(int l, float v) {
  return __int_as_float(__builtin_amdgcn_ds_bpermute(l << 2, __float_as_int(v)));
}
__device__ __forceinline__ int bpermi(int l, int v) {
  return __builtin_amdgcn_ds_bpermute(l << 2, v);
}
// Multiplexed butterfly merge: lanes with `hi` keep reducing b, others a.
__device__ __forceinline__ float merge2(float a, float b, bool hi, int xo) {
  const float keep = hi ? b : a;
  const float send = hi ? a : b;
  return keep + __shfl_xor(send, xo, 64);
}

#if __has_builtin(__builtin_amdgcn_fdot2)
__device__ __forceinline__ float fdot2(h2 a, h2 b, float c) {
  return __builtin_amdgcn_fdot2(a, b, c, false);
}
#else
__device__ __forceinline__ float fdot2(h2 a, h2 b, float c) {
  return fmaf((float)a.x, (float)b.x, fmaf((float)a.y, (float)b.y, c));
}
#endif

// ---------------------------------------------------------------------------
// Fused prep: blocks 0-1023 transpose feat (64,65536)f32 -> (65536,64)fp16;
// blocks 1024-2047 transpose lbs (21,262144)f32 -> (262144,21)fp16.
// ---------------------------------------------------------------------------
__global__ __launch_bounds__(256) void k_prep(const float* __restrict__ feat,
                                              const float* __restrict__ lbs,
                                              _Float16* __restrict__ feat_h,
                                              _Float16* __restrict__ lbs_h) {
  __shared__ float ldsf[64 * 65];
  const int l = threadIdx.x & 63;
  const int w = threadIdx.x >> 6;
  if (blockIdx.x < 1024) {
    float(*tile)[65] = (float(*)[65])ldsf;
    const int s0 = blockIdx.x * 64;
#pragma unroll
    for (int k = 0; k < 16; ++k) {
      const int d = w * 16 + k;
      tile[d][l] = feat[(size_t)d * M_TOT + s0 + l];
    }
    __syncthreads();
    const int lh = l & 31, hs = l >> 5;
    h2* out2 = (h2*)feat_h;
#pragma unroll
    for (int k = 0; k < 8; ++k) {
      const int s = w * 16 + 2 * k + hs;
      h2 v;
      v.x = (_Float16)tile[2 * lh][s];
      v.y = (_Float16)tile[2 * lh + 1][s];
      out2[(size_t)(s0 + s) * 32 + lh] = v;  // 256B coalesced
    }
  } else {
    _Float16* buf = ((_Float16*)ldsf) + w * (64 * 21);
    const int sb = (blockIdx.x - 1024) * 256 + w * 64;
#pragma unroll
    for (int c = 0; c < 21; ++c)
      buf[l * 21 + c] = (_Float16)lbs[(size_t)c * LBS_S + sb + l];
    __syncthreads();
    const uint32_t* src = (const uint32_t*)buf;
    uint32_t* dst = (uint32_t*)(lbs_h + (size_t)sb * 21);  // sb*42 B, dword-aligned
#pragma unroll
    for (int k = 0; k < 11; ++k) {
      const int i = k * 64 + l;
      if (i < 672) dst[i] = src[i];  // 672 dwords = 64 sites * 42 B
    }
  }
}

// ---------------------------------------------------------------------------
// N2[site] = ||feat_grid[:, site]||^2, quad-major: n2[(a*256+b)*4 + ey*2+ex].
// 8 quads per wave: lane = (group g = L>>3 -> quad, channel-block cb = L&7).
// ---------------------------------------------------------------------------
__global__ __launch_bounds__(256) void k_n2(const _Float16* __restrict__ feat_h,
                                            float* __restrict__ n2) {
  const int lane = threadIdx.x & 63;
  const int cb = lane & 7;
  const int g = lane >> 3;
  const int quad = blockIdx.x * 32 + (int)(threadIdx.x >> 6) * 8 + g;
  const int a = quad >> 8;
  const int b = quad & 255;
  const int ra[3] = {max(a - 1, 0), a, min(a + 1, 255)};
  const int cbn[3] = {max(b - 1, 0), b, min(b + 1, 255)};

  const h8* fp = (const h8*)feat_h;
  H8 F[3][3];
#pragma unroll
  for (int i = 0; i < 3; ++i)
#pragma unroll
    for (int j = 0; j < 3; ++j)
      F[i][j].v = fp[(size_t)((ra[i] << 8) + cbn[j]) * 8 + cb];

  h2 wyh[2], wxh[2];
  int cye[2], cxe[2];
#pragma unroll
  for (int e = 0; e < 2; ++e) {
    const float yf = fminf(fmaxf((float)(2 * a + e) * 0.5f - 0.25f, 0.0f), 255.0f);
    const int y0 = min((int)yf, 254);
    wyh[e].x = wyh[e].y = (_Float16)(yf - (float)y0);
    cye[e] = y0 - (a - 1);
    const float xf = fminf(fmaxf((float)(2 * b + e) * 0.5f - 0.25f, 0.0f), 255.0f);
    const int x0 = min((int)xf, 254);
    wxh[e].x = wxh[e].y = (_Float16)(xf - (float)x0);
    cxe[e] = x0 - (b - 1);
  }

  H8 colv[3][2];
#pragma unroll
  for (int r = 0; r < 3; ++r)
#pragma unroll
    for (int e = 0; e < 2; ++e) {
      const bool s1 = (cxe[e] == 1);
#pragma unroll
      for (int q = 0; q < 4; ++q) {
        const h2 A = s1 ? F[r][1].h[q] : F[r][0].h[q];
        const h2 B = s1 ? F[r][2].h[q] : F[r][1].h[q];
        colv[r][e].h[q] = A + wxh[e] * (B - A);
      }
    }

  float sq[4];
#pragma unroll
  for (int ey = 0; ey < 2; ++ey)
#pragma unroll
    for (int ex = 0; ex < 2; ++ex) {
      const bool s1 = (cye[ey] == 1);
      float nn = 0.0f;
#pragma unroll
      for (int q = 0; q < 4; ++q) {
        const h2 A = s1 ? colv[1][ex].h[q] : colv[0][ex].h[q];
        const h2 B = s1 ? colv[2][ex].h[q] : colv[1][ex].h[q];
        const h2 v = A + wyh[ey] * (B - A);
        nn = fdot2(v, v, nn);
      }
      sq[ey * 2 + ex] = nn;
    }

  const bool b0 = lane & 1, b1 = lane & 2;
  float m0 = merge2(sq[0], sq[1], b0, 1);
  float m1 = merge2(sq[2], sq[3], b0, 1);
  float mm = merge2(m0, m1, b1, 2);
  mm += __shfl_xor(mm, 4, 64);
  if ((lane & 7) < 4) n2[quad * 4 + (lane & 3)] = mm;
}

// ---------------------------------------------------------------------------
// Binning: sort pixels by 16x16 rp-bucket for gather locality.
// ---------------------------------------------------------------------------
__global__ __launch_bounds__(256) void k_hist(const float* __restrict__ grid_inte,
                                              const float* __restrict__ grid,
                                              int* __restrict__ keys,
                                              int* __restrict__ hist) {
  const int i = blockIdx.x * 256 + threadIdx.x;
  const float dx = grid[(2 * 512 + 2) * 2 + 0] - grid[(1 * 512 + 2) * 2 + 0];
  const float dy = grid[(2 * 512 + 2) * 2 + 1] - grid[(2 * 512 + 1) * 2 + 1];
  const int rp0 = (int)floorf(grid_inte[i * 2 + 0] / dx);
  const int rp1 = (int)floorf(grid_inte[i * 2 + 1] / dy);
  const int key = ((rp0 >> 4) << 5) | (rp1 >> 4);  // 32x32 bins
  keys[i] = key;
  atomicAdd(&hist[key], 1);
}

// Exclusive scan of 1024 bins -> cursor (single block, 256 threads).
__global__ __launch_bounds__(256) void k_scan(const int* __restrict__ hist,
                                              int* __restrict__ cursor) {
  __shared__ int wsum[4];
  const int t = threadIdx.x;
  const int4 h = ((const int4*)hist)[t];
  const int s = h.x + h.y + h.z + h.w;
  int sc = s;  // inclusive scan within the 64-lane wave
#pragma unroll
  for (int o = 1; o < 64; o <<= 1) {
    const int u = __shfl_up(sc, o, 64);
    if ((t & 63) >= o) sc += u;
  }
  if ((t & 63) == 63) wsum[t >> 6] = sc;
  __syncthreads();
  int base = 0;
  for (int wv = 0; wv < (t >> 6); ++wv) base += wsum[wv];
  const int ex = base + sc - s;
  cursor[4 * t + 0] = ex;
  cursor[4 * t + 1] = ex + h.x;
  cursor[4 * t + 2] = ex + h.x + h.y;
  cursor[4 * t + 3] = ex + h.x + h.y + h.z;
}

__global__ __launch_bounds__(256) void k_scatter(const int* __restrict__ keys,
                                                 int* __restrict__ cursor,
                                                 int* __restrict__ order) {
  const int i = blockIdx.x * 256 + threadIdx.x;
  const int pos = atomicAdd(&cursor[keys[i]], 1);
  order[pos] = i;
}

// ---------------------------------------------------------------------------
// Main kernel. One wave per pixel (pixels visited in bin-sorted order).
// Dot stage: lane = (site-group g = L>>3, channel-block cb = L&7); 8 ch/lane.
// After the reduce, lane L holds D'_s for s = 8*(L&1) + (L>>3).
// Tap stage: lane t < 25 handles tap (t/5, t%5). Vote: 3 taps x 21 classes.
// lbs/n2 loads are issued BEFORE the dot/exp chain (latency overlap).
// ---------------------------------------------------------------------------
__global__ __launch_bounds__(256) void k_main(const float* __restrict__ grid_inte,
                                              const float* __restrict__ grid,
                                              const _Float16* __restrict__ feat_h,
                                              const _Float16* __restrict__ lbs_h,
                                              const float* __restrict__ n2,
                                              const float* __restrict__ wei_p,
                                              const int* __restrict__ order,
                                              float* __restrict__ out) {
  const int lane = threadIdx.x & 63;
  const int bid = (int)blockIdx.x;
  // XCD-chunked swizzle: consecutive sorted blocks -> same XCD (16384 = 8*2048)
  const int bswz = ((bid & 7) << 11) | (bid >> 3);
  const int m = rfl(order[bswz * 4 + (int)(threadIdx.x >> 6)]);

  const float dx = grid[(2 * 512 + 2) * 2 + 0] - grid[(1 * 512 + 2) * 2 + 0];
  const float dy = grid[(2 * 512 + 2) * 2 + 1] - grid[(2 * 512 + 1) * 2 + 1];
  const float wei = wei_p[0];

  const float gi0 = grid_inte[m * 2 + 0];
  const float gi1 = grid_inte[m * 2 + 1];
  const int rp0 = rfl((int)floorf(gi0 / dx));
  const int rp1 = rfl((int)floorf(gi1 / dy));
  const int by = (rp0 - 3) >> 1;  // 4x4 patch base (scalar)
  const int bx = (rp1 - 3) >> 1;

  const int cb = lane & 7;
  const int g = lane >> 3;
  const h8* fp = (const h8*)feat_h;

  // ---- Issue feat loads (center + 2 patch) ----
  H8 C, P0, P1;
  C.v = fp[(size_t)m * 8 + cb];
  {
    const int s0 = g;
    const int yy0 = min(max(by + (s0 >> 2), 0), 255);
    const int xx0 = min(max(bx + (s0 & 3), 0), 255);
    P0.v = fp[(size_t)((yy0 << 8) + xx0) * 8 + cb];
    const int s1 = 8 + g;
    const int yy1 = min(max(by + (s1 >> 2), 0), 255);
    const int xx1 = min(max(bx + (s1 & 3), 0), 255);
    P1.v = fp[(size_t)((yy1 << 8) + xx1) * 8 + cb];
  }

  // ---- Tap geometry (VALU only, independent of feat loads) ----
  const int t = lane;
  const int ti = (t * 13) >> 6;  // t/5 for t < 25
  const int tj = t - 5 * ti;
  const int r5 = min(max(rp0 + ti - 2, 0), 511);
  const int c5 = min(max(rp1 + tj - 2, 0), 511);
  const float yf = fminf(fmaxf((float)r5 * 0.5f - 0.25f, 0.0f), 255.0f);
  const int y0 = min((int)yf, 254);
  const float wy = yf - (float)y0;
  const int qy = y0 - by;  // in [0,2] for t<25
  const float xf = fminf(fmaxf((float)c5 * 0.5f - 0.25f, 0.0f), 255.0f);
  const int x0 = min((int)xf, 254);
  const float wx = xf - (float)x0;
  const int qx = x0 - bx;
  const int lidx = r5 * 512 + c5;

  // ---- Issue n2 gather ----
  const float n2g = n2[(((r5 >> 1) << 8) + (c5 >> 1)) * 4 + ((r5 & 1) * 2 + (c5 & 1))];

  // ---- Prefetch the 9 lbs vote gathers (depend only on rp, not on dist) ----
  const int vg = (lane >= 42) ? 2 : ((lane >= 21) ? 1 : 0);
  const int cc = min(lane - 21 * vg, 20);
  float lg[9];
#pragma unroll
  for (int it = 0; it < 9; ++it) {
    const int tt = 3 * it + vg;          // taps 25,26 masked later via dist==0
    const int idxt = bpermi(tt, lidx);   // clamped coords -> in-bounds
    lg[it] = (float)lbs_h[idxt * 21 + cc];
  }

  // ---- Dot stage (consumes patch loads) ----
  float nhp = 0.0f;
#pragma unroll
  for (int q = 0; q < 4; ++q) nhp = fdot2(C.h[q], C.h[q], nhp);
  nhp *= -0.5f;
  float pa = nhp, pb = nhp;
#pragma unroll
  for (int q = 0; q < 4; ++q) {
    pa = fdot2(P0.h[q], C.h[q], pa);
    pb = fdot2(P1.h[q], C.h[q], pb);
  }
  float Dv = merge2(pa, pb, lane & 1, 1);
  Dv += __shfl_xor(Dv, 2, 64);
  Dv += __shfl_xor(Dv, 4, 64);
  // lane L holds D'_s, s = 8*(L&1) + (L>>3); source lane for s: ((s&7)<<3)|(s>>3)

  // ---- Bilinear in D' space, mse, dist ----
  const int s00 = qy * 4 + qx;
  const int s01 = s00 + 1, s10 = s00 + 4, s11 = s00 + 5;
  const int l00 = ((s00 & 7) << 3) | (s00 >> 3);
  const int l01 = ((s01 & 7) << 3) | (s01 >> 3);
  const int l10 = ((s10 & 7) << 3) | (s10 >> 3);
  const int l11 = ((s11 & 7) << 3) | (s11 >> 3);
  const float d00 = bperm(l00, Dv);
  const float d01 = bperm(l01, Dv);
  const float d10 = bperm(l10, Dv);
  const float d11 = bperm(l11, Dv);
  const float lo = fmaf(wx, d01 - d00, d00);
  const float hi = fmaf(wx, d11 - d10, d10);
  const float crossD = fmaf(wy, hi - lo, lo);

  const float mse = fmaf(-2.0f, crossD, n2g) * 0.015625f;  // /64
  float dist = __expf(-wei * mse);
  dist = (t < 25) ? dist : 0.0f;

  float den = dist;
#pragma unroll
  for (int o = 1; o < 64; o <<= 1) den += __shfl_xor(den, o, 64);

  // ---- Vote: fma with prefetched lg ----
  float vote = 0.0f;
#pragma unroll
  for (int it = 0; it < 9; ++it) {
    const float dt = bperm(3 * it + vg, dist);
    vote = fmaf(lg[it], dt, vote);
  }
  const float va = bperm(lane + 21, vote);
  const float vb = bperm(lane + 42, vote);
  const float vtot = vote + va + vb;

  if (lane < 21) out[lane * M_TOT + m] = vtot / fmaxf(den, 1e-15f);
}

extern "C" void kernel_launch(void* const* d_in, const int* in_sizes, int n_in,
                              void* d_out, int out_size, void* d_ws, size_t ws_size,
                              hipStream_t stream) {
  const float* grid_inte = (const float*)d_in[0];  // (1,256,256,2)
  const float* grid      = (const float*)d_in[1];  // (1,512,512,2)
  const float* feat      = (const float*)d_in[2];  // (1,64,256,256)
  const float* lbs       = (const float*)d_in[3];  // (1,21,512,512)
  const float* wei       = (const float*)d_in[4];  // scalar
  float* out = (float*)d_out;                      // (1,21,256,256)

  char* ws = (char*)d_ws;
  _Float16* feat_h = (_Float16*)ws;                         // 8,388,608 B
  _Float16* lbs_h  = (_Float16*)(ws + 8388608);             // 11,010,048 B
  float*    n2v    = (float*)(ws + 19398656);               // 1,048,576 B
  int*      keys   = (int*)(ws + 20447232);                 // 262,144 B
  int*      order  = (int*)(ws + 20709376);                 // 262,144 B
  int*      hist   = (int*)(ws + 20971520);                 // 4,096 B (16B-aligned)
  int*      cursor = (int*)(ws + 20975616);                 // 4,096 B

  hipMemsetAsync(hist, 0, NBINS * sizeof(int), stream);
  hipLaunchKernelGGL(k_prep, dim3(2048), dim3(256), 0, stream, feat, lbs, feat_h, lbs_h);
  hipLaunchKernelGGL(k_n2, dim3(M_TOT / 32), dim3(256), 0, stream, feat_h, n2v);
  hipLaunchKernelGGL(k_hist, dim3(M_TOT / 256), dim3(256), 0, stream, grid_inte, grid, keys, hist);
  hipLaunchKernelGGL(k_scan, dim3(1), dim3(256), 0, stream, hist, cursor);
  hipLaunchKernelGGL(k_scatter, dim3(M_TOT / 256), dim3(256), 0, stream, keys, cursor, order);
  hipLaunchKernelGGL(k_main, dim3(M_TOT / 4), dim3(256), 0, stream,
                     grid_inte, grid, feat_h, lbs_h, n2v, wei, order, out);
}

// Round 6
// 79.796 us; speedup vs baseline: 1.0679x; 1.0679x over previous
//
#include <hip/hip_runtime.h>

// Problem constants (N=1, D=64, NCLS=21, R=C=512, R_IN=C_IN=256)
#define M_TOT 65536   // R_IN*C_IN
#define LBS_S 262144  // R*C
#define NBINS 1024    // 32x32 bins of 16x16 rp-sites

typedef _Float16 h2 __attribute__((ext_vector_type(2)));
typedef _Float16 h8 __attribute__((ext_vector_type(8)));
union H8 { h8 v; h2 h[4]; };

__device__ __forceinline__ int rfl(int v) { return __builtin_amdgcn_readfirstlane(v); }
__device__ __forceinline__ float bperm(int l, float v) {
  return __int_as_float(__builtin_amdgcn_ds_bpermute(l << 2, __float_as_int(v)));
}
__device__ __forceinline__ int bpermi(int l, int v) {
  return __builtin_amdgcn_ds_bpermute(l << 2, v);
}
// Multiplexed butterfly merge: lanes with `hi` keep reducing b, others a.
__device__ __forceinline__ float merge2(float a, float b, bool hi, int xo) {
  const float keep = hi ? b : a;
  const float send = hi ? a : b;
  return keep + __shfl_xor(send, xo, 64);
}

#if __has_builtin(__builtin_amdgcn_fdot2)
__device__ __forceinline__ float fdot2(h2 a, h2 b, float c) {
  return __builtin_amdgcn_fdot2(a, b, c, false);
}
#else
__device__ __forceinline__ float fdot2(h2 a, h2 b, float c) {
  return fmaf((float)a.x, (float)b.x, fmaf((float)a.y, (float)b.y, c));
}
#endif

// ---------------------------------------------------------------------------
// Fused prep: blocks 0-1023 transpose feat (64,65536)f32 -> (65536,64)fp16;
// blocks 1024-2047 transpose lbs (21,262144)f32 -> (262144,21)fp16.
// Block 0 additionally zeroes the 1024-bin histogram (stream order guarantees
// completion before k_hist's atomics).
// ---------------------------------------------------------------------------
__global__ __launch_bounds__(256) void k_prep(const float* __restrict__ feat,
                                              const float* __restrict__ lbs,
                                              _Float16* __restrict__ feat_h,
                                              _Float16* __restrict__ lbs_h,
                                              int* __restrict__ hist) {
  __shared__ float ldsf[64 * 65];
  const int l = threadIdx.x & 63;
  const int w = threadIdx.x >> 6;
  if (blockIdx.x == 0) {
#pragma unroll
    for (int k = 0; k < 4; ++k) hist[k * 256 + threadIdx.x] = 0;
  }
  if (blockIdx.x < 1024) {
    float(*tile)[65] = (float(*)[65])ldsf;
    const int s0 = blockIdx.x * 64;
#pragma unroll
    for (int k = 0; k < 16; ++k) {
      const int d = w * 16 + k;
      tile[d][l] = feat[(size_t)d * M_TOT + s0 + l];
    }
    __syncthreads();
    const int lh = l & 31, hs = l >> 5;
    h2* out2 = (h2*)feat_h;
#pragma unroll
    for (int k = 0; k < 8; ++k) {
      const int s = w * 16 + 2 * k + hs;
      h2 v;
      v.x = (_Float16)tile[2 * lh][s];
      v.y = (_Float16)tile[2 * lh + 1][s];
      out2[(size_t)(s0 + s) * 32 + lh] = v;  // 256B coalesced
    }
  } else {
    _Float16* buf = ((_Float16*)ldsf) + w * (64 * 21);
    const int sb = (blockIdx.x - 1024) * 256 + w * 64;
#pragma unroll
    for (int c = 0; c < 21; ++c)
      buf[l * 21 + c] = (_Float16)lbs[(size_t)c * LBS_S + sb + l];
    __syncthreads();
    const uint32_t* src = (const uint32_t*)buf;
    uint32_t* dst = (uint32_t*)(lbs_h + (size_t)sb * 21);  // sb*42 B, dword-aligned
#pragma unroll
    for (int k = 0; k < 11; ++k) {
      const int i = k * 64 + l;
      if (i < 672) dst[i] = src[i];  // 672 dwords = 64 sites * 42 B
    }
  }
}

// ---------------------------------------------------------------------------
// N2[site] = ||feat_grid[:, site]||^2, quad-major: n2[(a*256+b)*4 + ey*2+ex].
// 8 quads per wave: lane = (group g = L>>3 -> quad, channel-block cb = L&7).
// ---------------------------------------------------------------------------
__global__ __launch_bounds__(256) void k_n2(const _Float16* __restrict__ feat_h,
                                            float* __restrict__ n2) {
  const int lane = threadIdx.x & 63;
  const int cb = lane & 7;
  const int g = lane >> 3;
  const int quad = blockIdx.x * 32 + (int)(threadIdx.x >> 6) * 8 + g;
  const int a = quad >> 8;
  const int b = quad & 255;
  const int ra[3] = {max(a - 1, 0), a, min(a + 1, 255)};
  const int cbn[3] = {max(b - 1, 0), b, min(b + 1, 255)};

  const h8* fp = (const h8*)feat_h;
  H8 F[3][3];
#pragma unroll
  for (int i = 0; i < 3; ++i)
#pragma unroll
    for (int j = 0; j < 3; ++j)
      F[i][j].v = fp[(size_t)((ra[i] << 8) + cbn[j]) * 8 + cb];

  h2 wyh[2], wxh[2];
  int cye[2], cxe[2];
#pragma unroll
  for (int e = 0; e < 2; ++e) {
    const float yf = fminf(fmaxf((float)(2 * a + e) * 0.5f - 0.25f, 0.0f), 255.0f);
    const int y0 = min((int)yf, 254);
    wyh[e].x = wyh[e].y = (_Float16)(yf - (float)y0);
    cye[e] = y0 - (a - 1);
    const float xf = fminf(fmaxf((float)(2 * b + e) * 0.5f - 0.25f, 0.0f), 255.0f);
    const int x0 = min((int)xf, 254);
    wxh[e].x = wxh[e].y = (_Float16)(xf - (float)x0);
    cxe[e] = x0 - (b - 1);
  }

  H8 colv[3][2];
#pragma unroll
  for (int r = 0; r < 3; ++r)
#pragma unroll
    for (int e = 0; e < 2; ++e) {
      const bool s1 = (cxe[e] == 1);
#pragma unroll
      for (int q = 0; q < 4; ++q) {
        const h2 A = s1 ? F[r][1].h[q] : F[r][0].h[q];
        const h2 B = s1 ? F[r][2].h[q] : F[r][1].h[q];
        colv[r][e].h[q] = A + wxh[e] * (B - A);
      }
    }

  float sq[4];
#pragma unroll
  for (int ey = 0; ey < 2; ++ey)
#pragma unroll
    for (int ex = 0; ex < 2; ++ex) {
      const bool s1 = (cye[ey] == 1);
      float nn = 0.0f;
#pragma unroll
      for (int q = 0; q < 4; ++q) {
        const h2 A = s1 ? colv[1][ex].h[q] : colv[0][ex].h[q];
        const h2 B = s1 ? colv[2][ex].h[q] : colv[1][ex].h[q];
        const h2 v = A + wyh[ey] * (B - A);
        nn = fdot2(v, v, nn);
      }
      sq[ey * 2 + ex] = nn;
    }

  const bool b0 = lane & 1, b1 = lane & 2;
  float m0 = merge2(sq[0], sq[1], b0, 1);
  float m1 = merge2(sq[2], sq[3], b0, 1);
  float mm = merge2(m0, m1, b1, 2);
  mm += __shfl_xor(mm, 4, 64);
  if ((lane & 7) < 4) n2[quad * 4 + (lane & 3)] = mm;
}

// ---------------------------------------------------------------------------
// Binning: sort pixels by 16x16 rp-bucket for gather locality.
// ---------------------------------------------------------------------------
__device__ __forceinline__ int pixel_key(const float* grid_inte, const float* grid, int i) {
  const float dx = grid[(2 * 512 + 2) * 2 + 0] - grid[(1 * 512 + 2) * 2 + 0];
  const float dy = grid[(2 * 512 + 2) * 2 + 1] - grid[(2 * 512 + 1) * 2 + 1];
  const int rp0 = (int)floorf(grid_inte[i * 2 + 0] / dx);
  const int rp1 = (int)floorf(grid_inte[i * 2 + 1] / dy);
  return ((rp0 >> 4) << 5) | (rp1 >> 4);  // 32x32 bins
}

__global__ __launch_bounds__(256) void k_hist(const float* __restrict__ grid_inte,
                                              const float* __restrict__ grid,
                                              int* __restrict__ hist) {
  const int i = blockIdx.x * 256 + threadIdx.x;
  atomicAdd(&hist[pixel_key(grid_inte, grid, i)], 1);
}

// Exclusive scan of 1024 bins -> cursor (single block, 256 threads).
__global__ __launch_bounds__(256) void k_scan(const int* __restrict__ hist,
                                              int* __restrict__ cursor) {
  __shared__ int wsum[4];
  const int t = threadIdx.x;
  const int4 h = ((const int4*)hist)[t];
  const int s = h.x + h.y + h.z + h.w;
  int sc = s;  // inclusive scan within the 64-lane wave
#pragma unroll
  for (int o = 1; o < 64; o <<= 1) {
    const int u = __shfl_up(sc, o, 64);
    if ((t & 63) >= o) sc += u;
  }
  if ((t & 63) == 63) wsum[t >> 6] = sc;
  __syncthreads();
  int base = 0;
  for (int wv = 0; wv < (t >> 6); ++wv) base += wsum[wv];
  const int ex = base + sc - s;
  cursor[4 * t + 0] = ex;
  cursor[4 * t + 1] = ex + h.x;
  cursor[4 * t + 2] = ex + h.x + h.y;
  cursor[4 * t + 3] = ex + h.x + h.y + h.z;
}

__global__ __launch_bounds__(256) void k_scatter(const float* __restrict__ grid_inte,
                                                 const float* __restrict__ grid,
                                                 int* __restrict__ cursor,
                                                 int* __restrict__ order) {
  const int i = blockIdx.x * 256 + threadIdx.x;
  const int pos = atomicAdd(&cursor[pixel_key(grid_inte, grid, i)], 1);
  order[pos] = i;
}

// ---------------------------------------------------------------------------
// Main kernel. One wave per pixel (pixels visited in bin-sorted order).
// Dot stage: lane = (site-group g = L>>3, channel-block cb = L&7); 8 ch/lane.
// After the reduce, lane L holds D'_s for s = 8*(L&1) + (L>>3).
// Tap stage: lane t < 25 handles tap (t/5, t%5). Vote: 3 taps x 21 classes.
// lbs/n2 loads are issued BEFORE the dot/exp chain (latency overlap).
// ---------------------------------------------------------------------------
__global__ __launch_bounds__(256) void k_main(const float* __restrict__ grid_inte,
                                              const float* __restrict__ grid,
                                              const _Float16* __restrict__ feat_h,
                                              const _Float16* __restrict__ lbs_h,
                                              const float* __restrict__ n2,
                                              const float* __restrict__ wei_p,
                                              const int* __restrict__ order,
                                              float* __restrict__ out) {
  const int lane = threadIdx.x & 63;
  const int bid = (int)blockIdx.x;
  // XCD-chunked swizzle: consecutive sorted blocks -> same XCD (16384 = 8*2048)
  const int bswz = ((bid & 7) << 11) | (bid >> 3);
  const int m = rfl(order[bswz * 4 + (int)(threadIdx.x >> 6)]);

  const float dx = grid[(2 * 512 + 2) * 2 + 0] - grid[(1 * 512 + 2) * 2 + 0];
  const float dy = grid[(2 * 512 + 2) * 2 + 1] - grid[(2 * 512 + 1) * 2 + 1];
  const float wei = wei_p[0];

  const float gi0 = grid_inte[m * 2 + 0];
  const float gi1 = grid_inte[m * 2 + 1];
  const int rp0 = rfl((int)floorf(gi0 / dx));
  const int rp1 = rfl((int)floorf(gi1 / dy));
  const int by = (rp0 - 3) >> 1;  // 4x4 patch base (scalar)
  const int bx = (rp1 - 3) >> 1;

  const int cb = lane & 7;
  const int g = lane >> 3;
  const h8* fp = (const h8*)feat_h;

  // ---- Issue feat loads (center + 2 patch) ----
  H8 C, P0, P1;
  C.v = fp[(size_t)m * 8 + cb];
  {
    const int s0 = g;
    const int yy0 = min(max(by + (s0 >> 2), 0), 255);
    const int xx0 = min(max(bx + (s0 & 3), 0), 255);
    P0.v = fp[(size_t)((yy0 << 8) + xx0) * 8 + cb];
    const int s1 = 8 + g;
    const int yy1 = min(max(by + (s1 >> 2), 0), 255);
    const int xx1 = min(max(bx + (s1 & 3), 0), 255);
    P1.v = fp[(size_t)((yy1 << 8) + xx1) * 8 + cb];
  }

  // ---- Tap geometry (VALU only, independent of feat loads) ----
  const int t = lane;
  const int ti = (t * 13) >> 6;  // t/5 for t < 25
  const int tj = t - 5 * ti;
  const int r5 = min(max(rp0 + ti - 2, 0), 511);
  const int c5 = min(max(rp1 + tj - 2, 0), 511);
  const float yf = fminf(fmaxf((float)r5 * 0.5f - 0.25f, 0.0f), 255.0f);
  const int y0 = min((int)yf, 254);
  const float wy = yf - (float)y0;
  const int qy = y0 - by;  // in [0,2] for t<25
  const float xf = fminf(fmaxf((float)c5 * 0.5f - 0.25f, 0.0f), 255.0f);
  const int x0 = min((int)xf, 254);
  const float wx = xf - (float)x0;
  const int qx = x0 - bx;
  const int lidx = r5 * 512 + c5;

  // ---- Issue n2 gather ----
  const float n2g = n2[(((r5 >> 1) << 8) + (c5 >> 1)) * 4 + ((r5 & 1) * 2 + (c5 & 1))];

  // ---- Prefetch the 9 lbs vote gathers (depend only on rp, not on dist) ----
  const int vg = (lane >= 42) ? 2 : ((lane >= 21) ? 1 : 0);
  const int cc = min(lane - 21 * vg, 20);
  float lg[9];
#pragma unroll
  for (int it = 0; it < 9; ++it) {
    const int tt = 3 * it + vg;          // taps 25,26 masked later via dist==0
    const int idxt = bpermi(tt, lidx);   // clamped coords -> in-bounds
    lg[it] = (float)lbs_h[idxt * 21 + cc];
  }

  // ---- Dot stage (consumes patch loads) ----
  float nhp = 0.0f;
#pragma unroll
  for (int q = 0; q < 4; ++q) nhp = fdot2(C.h[q], C.h[q], nhp);
  nhp *= -0.5f;
  float pa = nhp, pb = nhp;
#pragma unroll
  for (int q = 0; q < 4; ++q) {
    pa = fdot2(P0.h[q], C.h[q], pa);
    pb = fdot2(P1.h[q], C.h[q], pb);
  }
  float Dv = merge2(pa, pb, lane & 1, 1);
  Dv += __shfl_xor(Dv, 2, 64);
  Dv += __shfl_xor(Dv, 4, 64);
  // lane L holds D'_s, s = 8*(L&1) + (L>>3); source lane for s: ((s&7)<<3)|(s>>3)

  // ---- Bilinear in D' space, mse, dist ----
  const int s00 = qy * 4 + qx;
  const int s01 = s00 + 1, s10 = s00 + 4, s11 = s00 + 5;
  const int l00 = ((s00 & 7) << 3) | (s00 >> 3);
  const int l01 = ((s01 & 7) << 3) | (s01 >> 3);
  const int l10 = ((s10 & 7) << 3) | (s10 >> 3);
  const int l11 = ((s11 & 7) << 3) | (s11 >> 3);
  const float d00 = bperm(l00, Dv);
  const float d01 = bperm(l01, Dv);
  const float d10 = bperm(l10, Dv);
  const float d11 = bperm(l11, Dv);
  const float lo = fmaf(wx, d01 - d00, d00);
  const float hi = fmaf(wx, d11 - d10, d10);
  const float crossD = fmaf(wy, hi - lo, lo);

  const float mse = fmaf(-2.0f, crossD, n2g) * 0.015625f;  // /64
  float dist = __expf(-wei * mse);
  dist = (t < 25) ? dist : 0.0f;

  float den = dist;
#pragma unroll
  for (int o = 1; o < 64; o <<= 1) den += __shfl_xor(den, o, 64);

  // ---- Vote: fma with prefetched lg ----
  float vote = 0.0f;
#pragma unroll
  for (int it = 0; it < 9; ++it) {
    const float dt = bperm(3 * it + vg, dist);
    vote = fmaf(lg[it], dt, vote);
  }
  const float va = bperm(lane + 21, vote);
  const float vb = bperm(lane + 42, vote);
  const float vtot = vote + va + vb;

  if (lane < 21) out[lane * M_TOT + m] = vtot / fmaxf(den, 1e-15f);
}

extern "C" void kernel_launch(void* const* d_in, const int* in_sizes, int n_in,
                              void* d_out, int out_size, void* d_ws, size_t ws_size,
                              hipStream_t stream) {
  const float* grid_inte = (const float*)d_in[0];  // (1,256,256,2)
  const float* grid      = (const float*)d_in[1];  // (1,512,512,2)
  const float* feat      = (const float*)d_in[2];  // (1,64,256,256)
  const float* lbs       = (const float*)d_in[3];  // (1,21,512,512)
  const float* wei       = (const float*)d_in[4];  // scalar
  float* out = (float*)d_out;                      // (1,21,256,256)

  char* ws = (char*)d_ws;
  _Float16* feat_h = (_Float16*)ws;                         // 8,388,608 B
  _Float16* lbs_h  = (_Float16*)(ws + 8388608);             // 11,010,048 B
  float*    n2v    = (float*)(ws + 19398656);               // 1,048,576 B
  int*      order  = (int*)(ws + 20447232);                 // 262,144 B
  int*      hist   = (int*)(ws + 20709376);                 // 4,096 B (16B-aligned)
  int*      cursor = (int*)(ws + 20713472);                 // 4,096 B

  hipLaunchKernelGGL(k_prep, dim3(2048), dim3(256), 0, stream, feat, lbs, feat_h, lbs_h, hist);
  hipLaunchKernelGGL(k_n2, dim3(M_TOT / 32), dim3(256), 0, stream, feat_h, n2v);
  hipLaunchKernelGGL(k_hist, dim3(M_TOT / 256), dim3(256), 0, stream, grid_inte, grid, hist);
  hipLaunchKernelGGL(k_scan, dim3(1), dim3(256), 0, stream, hist, cursor);
  hipLaunchKernelGGL(k_scatter, dim3(M_TOT / 256), dim3(256), 0, stream, grid_inte, grid, cursor, order);
  hipLaunchKernelGGL(k_main, dim3(M_TOT / 4), dim3(256), 0, stream,
                     grid_inte, grid, feat_h, lbs_h, n2v, wei, order, out);
}